// Round 16
// baseline (508.312 us; speedup 1.0000x reference)
//
#include <hip/hip_runtime.h>
#include <hip/hip_bf16.h>
#include <stdint.h>

// Problem constants (match setup_inputs)
#define M_ROWS 100352   // 2048 * 49
#define C_DIM  512
#define QKV_N  1536
#define NH     16
#define HD     32
#define NWIN   49       // window tokens (7*7)
#define NMASK  64

typedef __attribute__((ext_vector_type(4))) float        f32x4;
typedef __attribute__((ext_vector_type(8))) short        bf16x8;
typedef __attribute__((ext_vector_type(4))) unsigned int u32x4;

static __device__ __forceinline__ unsigned short f32_to_bf16(float f) {
  union { float f; unsigned int u; } v; v.f = f;
  unsigned int u = v.u;
  return (unsigned short)((u + 0x7FFFu + ((u >> 16) & 1u)) >> 16);  // RNE
}

// global -> LDS direct DMA, 16B per lane. dest = wave-uniform base + lane*16.
static __device__ __forceinline__ void gload_lds16(const void* g, void* l) {
  __builtin_amdgcn_global_load_lds(
      (const __attribute__((address_space(1))) unsigned int*)g,
      (__attribute__((address_space(3))) unsigned int*)l, 16, 0, 0);
}

// ---------------------------------------------------------------- k_cvt
__global__ void k_cvt(const float* __restrict__ in, unsigned short* __restrict__ out, int n4) {
  int i = blockIdx.x * blockDim.x + threadIdx.x;
  int stride = gridDim.x * blockDim.x;
  for (; i < n4; i += stride) {
    float4 v = ((const float4*)in)[i];
    ushort4 o = make_ushort4(f32_to_bf16(v.x), f32_to_bf16(v.y),
                             f32_to_bf16(v.z), f32_to_bf16(v.w));
    ((ushort4*)out)[i] = o;
  }
}

// ------------------------------------------- transpose + convert weights
// in: K x N f32 (row-major), out: N x K bf16 (row-major) == B^T
__global__ void k_transpose_cvt(const float* __restrict__ in, unsigned short* __restrict__ out,
                                int K, int N) {
  __shared__ float t[32][33];
  const int n0 = blockIdx.x * 32, k0 = blockIdx.y * 32;
  const int tx = threadIdx.x & 31, ty = threadIdx.x >> 5;  // 32 x 8
#pragma unroll
  for (int rr = 0; rr < 32; rr += 8)
    t[ty + rr][tx] = in[(size_t)(k0 + ty + rr) * N + n0 + tx];
  __syncthreads();
#pragma unroll
  for (int rr = 0; rr < 32; rr += 8)
    out[(size_t)(n0 + ty + rr) * K + k0 + tx] = f32_to_bf16(t[tx][ty + rr]);
}

// ---------------------------- padded mask table: mskP[w][64][64], -1e30 pad
__global__ __launch_bounds__(256) void k_mskp(const float* __restrict__ mask,
                                              float* __restrict__ mskP) {
  const int idx = blockIdx.x * 256 + threadIdx.x;   // w<<12 | i<<6 | j
  const int j = idx & 63, i = (idx >> 6) & 63, w = idx >> 12;
  float v = -1e30f;
  if (i < NWIN && j < NWIN) v = mask[w * (NWIN * NWIN) + i * NWIN + j];
  mskP[idx] = v;
}

// ---------------------------- padded bias table: biasP[h][64][64], 0 pad
__global__ __launch_bounds__(256) void k_biasp(const float* __restrict__ rel,
                                               float* __restrict__ biasP) {
  const int idx = blockIdx.x * 256 + threadIdx.x;   // h<<12 | i<<6 | j
  const int j = idx & 63, i = (idx >> 6) & 63, h = idx >> 12;
  float v = 0.f;
  if (i < NWIN && j < NWIN) {
    const int rpi = ((j / 7) - (i / 7) + 6) * 13;
    v = rel[rpi * NH + h];
  }
  biasP[idx] = v;
}

#define WAITB(N)                                              \
  do {                                                        \
    asm volatile("s_waitcnt vmcnt(" #N ")" ::: "memory");     \
    __builtin_amdgcn_sched_barrier(0);                        \
    __builtin_amdgcn_s_barrier();                             \
    __builtin_amdgcn_sched_barrier(0);                        \
  } while (0)

// ------------------------------------------------------------------ GEMM
// EXACT r5/r12 4-phase 256x256 K-loop (schedule-fragile; never touched).
// OUT_MODE: 0 = f32 row-major, 1 = bf16 row-major,
//           2 = bf16 qkv-blocked [b][h][{q,k,v}][49][32] (attn-friendly).
template <int OUT_MODE>
static __device__ __forceinline__ void gemm256_body(const unsigned short* __restrict__ A,
                                                    const unsigned short* __restrict__ BT,
                                                    const float* __restrict__ bias,
                                                    void* __restrict__ Cout,
                                                    int M, int N, int K,
                                                    unsigned short* lds0) {
  unsigned short (*lds)[2][16384] = (unsigned short (*)[2][16384])lds0;
  const int tid = threadIdx.x;
  const int lane = tid & 63, wave = tid >> 6;
  const int wr = wave >> 2, wc = wave & 3;      // 2 x 4 wave grid
  const int lr = lane & 15, lg = lane >> 4;

  // bijective XCD swizzle (gridDim.x % 8 == 0 for all call sites)
  const int nwg = gridDim.x, q8 = nwg >> 3;
  const int wg = (blockIdx.x & 7) * q8 + (blockIdx.x >> 3);
  const int gx = N >> 8;
  const int bx = wg % gx, by = wg / gx;
  const int m0 = by << 8, n0 = bx << 8;

  const int srow = lane & 15;
  const int scol = (lane >> 4) * 8;
  const int sRG = wave >> 1;
  const int scg = wave & 1;

  const f32x4 fz = {0.f, 0.f, 0.f, 0.f};
  f32x4 acc[8][4];
#pragma unroll
  for (int i = 0; i < 8; ++i)
#pragma unroll
    for (int j = 0; j < 4; ++j) acc[i][j] = fz;

  const int NT = K >> 6;

  auto stageU = [&](const unsigned short* G, int gbase, int op, int t, int u) {
    const int RG = 4 * u + sRG;  // row-group 0..15
    gload_lds16(G + (size_t)(gbase + RG * 16 + srow) * K + (t << 6) + scg * 32 + scol,
                &lds[t & 1][op][(RG >> 3) * 8192 + (((RG & 7) << 1) + scg) * 512]);
  };

  const int roff = lg * 128 + lr * 8;

  bf16x8 af[4][2];
  bf16x8 bf[2][2];
  bf16x8 bg[2][2];

#define LDA(h, mh)                                                              \
  do {                                                                          \
    const unsigned short* la = &lds[(h) & 1][0][wr * 8192];                     \
    _Pragma("unroll") for (int m = 0; m < 4; ++m)                               \
    _Pragma("unroll") for (int ks = 0; ks < 2; ++ks)                            \
        af[m][ks] = *(const bf16x8*)(la + ((((mh)*4 + m) * 2 + ks) * 512) + roff); \
  } while (0)

#define LDB(h, nh, DST)                                                         \
  do {                                                                          \
    const unsigned short* lb = &lds[(h) & 1][1][(wc >> 1) * 8192];              \
    _Pragma("unroll") for (int n = 0; n < 2; ++n)                               \
    _Pragma("unroll") for (int ks = 0; ks < 2; ++ks)                            \
        DST[n][ks] = *(const bf16x8*)(lb + ((((wc & 1) * 4 + (nh)*2 + n) * 2 + ks) * 512) + roff); \
  } while (0)

#define MFMA16(mh, nh, B)                                                       \
  do {                                                                          \
    __builtin_amdgcn_s_setprio(1);                                              \
    _Pragma("unroll") for (int m = 0; m < 4; ++m)                               \
    _Pragma("unroll") for (int n = 0; n < 2; ++n)                               \
    _Pragma("unroll") for (int ks = 0; ks < 2; ++ks)                            \
        acc[(mh)*4 + m][(nh)*2 + n] = __builtin_amdgcn_mfma_f32_16x16x32_bf16(  \
            af[m][ks], B[n][ks], acc[(mh)*4 + m][(nh)*2 + n], 0, 0, 0);         \
    __builtin_amdgcn_s_setprio(0);                                              \
  } while (0)

  // prologue: tile 0, unit order B0 B1 B2 B3 A0 A2 A1 A3 (8 loads/lane)
  stageU(BT, n0, 1, 0, 0); stageU(BT, n0, 1, 0, 1);
  stageU(BT, n0, 1, 0, 2); stageU(BT, n0, 1, 0, 3);
  stageU(A,  m0, 0, 0, 0); stageU(A,  m0, 0, 0, 2);
  stageU(A,  m0, 0, 0, 1); stageU(A,  m0, 0, 0, 3);

  for (int h = 0; h < NT - 1; ++h) {
    const int t1 = h + 1;
    WAITB(2);
    stageU(BT, n0, 1, t1, 0); stageU(BT, n0, 1, t1, 1);
    LDA(h, 0);
    LDB(h, 0, bf);
    MFMA16(0, 0, bf);
    stageU(BT, n0, 1, t1, 2); stageU(BT, n0, 1, t1, 3);
    LDB(h, 1, bg);
    MFMA16(0, 1, bg);
    WAITB(4);
    stageU(A, m0, 0, t1, 0); stageU(A, m0, 0, t1, 2);
    LDA(h, 1);
    MFMA16(1, 1, bg);
    stageU(A, m0, 0, t1, 1); stageU(A, m0, 0, t1, 3);
    LDB(h, 0, bf);
    MFMA16(1, 0, bf);
  }
  {  // last tile, peeled
    const int h = NT - 1;
    WAITB(2);
    LDA(h, 0);
    LDB(h, 0, bf);
    MFMA16(0, 0, bf);
    LDB(h, 1, bg);
    MFMA16(0, 1, bg);
    WAITB(0);
    LDA(h, 1);
    MFMA16(1, 1, bg);
    LDB(h, 0, bf);
    MFMA16(1, 0, bf);
  }
#undef LDA
#undef LDB
#undef MFMA16

  float bv[4];
#pragma unroll
  for (int nj = 0; nj < 4; ++nj) bv[nj] = bias[n0 + wc * 64 + nj * 16 + lr];
#pragma unroll
  for (int mi = 0; mi < 8; ++mi)
#pragma unroll
    for (int nj = 0; nj < 4; ++nj)
#pragma unroll
      for (int r = 0; r < 4; ++r) {
        const int row = m0 + wr * 128 + mi * 16 + 4 * lg + r;
        const int col = n0 + wc * 64 + nj * 16 + lr;
        const float v = acc[mi][nj][r] + bv[nj];
        if (OUT_MODE == 2) {
          // qkv-blocked: row -> (b = row/49, i = row%49); col -> (which, h, d)
          const unsigned int b = (unsigned int)row / 49u;
          const unsigned int i = (unsigned int)row - b * 49u;
          const int which = col >> 9, hh = (col >> 5) & 15, d = col & 31;
          ((unsigned short*)Cout)[(((size_t)b * NH + hh) * 147 + which * 49 + i) * 32 + d] =
              f32_to_bf16(v);
        } else if (OUT_MODE == 1) {
          ((unsigned short*)Cout)[(size_t)row * N + col] = f32_to_bf16(v);
        } else {
          ((float*)Cout)[(size_t)row * N + col] = v;
        }
      }
}

__global__ __launch_bounds__(512, 2) void k_gemm_qkv(const unsigned short* __restrict__ A,
                                                     const unsigned short* __restrict__ BT,
                                                     const float* __restrict__ bias,
                                                     void* __restrict__ Cout,
                                                     int M, int N, int K) {
  __shared__ __align__(16) unsigned short lds[2][2][16384];  // 128 KB
  gemm256_body<2>(A, BT, bias, Cout, M, N, K, &lds[0][0][0]);
}

__global__ __launch_bounds__(512, 2) void k_gemm_proj(const unsigned short* __restrict__ A,
                                                      const unsigned short* __restrict__ BT,
                                                      const float* __restrict__ bias,
                                                      void* __restrict__ Cout,
                                                      int M, int N, int K) {
  __shared__ __align__(16) unsigned short lds[2][2][16384];  // 128 KB
  gemm256_body<0>(A, BT, bias, Cout, M, N, K, &lds[0][0][0]);
}

// ------------------------------------------------------------- attention
// Block = (b, hg): 8 waves (512 thr) handle h = 8*hg + wave for ONE window
// b -> the block's qkv reads are a CONTIGUOUS 75 KB ([b][8hg..8hg+8) of the
// blocked layout), and consecutive blocks stream qkvb linearly (no swizzle:
// table working set mskP 1MB + biasP 0.26MB is L2-resident on every XCD).
// mask staged once per block into LDS (16.5 KB, shared by all 8 waves);
// bias[h] added from global (L2-hit f32x4 per 4 scores).  LDS: msk 16.5K +
// merged P/V 8x4.125K = 49.5 KB -> 3 blocks/CU.  V register-resident before
// the barrier; P reuses V's LDS region (r15-verified).  setprio on MFMA.
__global__ __launch_bounds__(512) void k_attn(const unsigned short* __restrict__ qkv,
                                              const float* __restrict__ mskP,
                                              const float* __restrict__ biasP,
                                              unsigned short* __restrict__ aout) {
  const int wave = threadIdx.x >> 6, lane = threadIdx.x & 63;
  const int lr = lane & 15, lg = lane >> 4;

  const int b = blockIdx.x >> 1, hg = blockIdx.x & 1;
  const int h = hg * 8 + wave;
  const int w = b & 63;

  __shared__ float msk[64 * 66];                        // 16.5 KB shared mask
  __shared__ __align__(16) unsigned short PV[8][2112];  // per-wave V^T, then P
  unsigned short* vt = PV[wave];
  unsigned short* pl = PV[wave];   // P reuses V's region after vfr load

  // ---- stage mskP(w) -> LDS (coalesced 16 KB read; issued first) ----
  const float* tblm = mskP + ((size_t)w << 12);
#pragma unroll
  for (int it = 0; it < 2; ++it) {
    const int c = threadIdx.x + 512 * it;   // 16B chunk 0..1023
    const int row = c >> 4, col4 = c & 15;
    const f32x4 t4 = *(const f32x4*)(tblm + row * 64 + col4 * 4);
    float* dst = &msk[row * 66 + col4 * 4];
    dst[0] = t4[0]; dst[1] = t4[1]; dst[2] = t4[2]; dst[3] = t4[3];
  }

  const unsigned short* qp = qkv + ((size_t)(b * NH + h) * 147) * 32;
  const unsigned short* kp = qp + 49 * 32;
  const unsigned short* vp = qp + 2 * 49 * 32;

  bf16x8 kf[4], qf[4];
#pragma unroll
  for (int t = 0; t < 4; ++t) {
    kf[t] = *(const bf16x8*)(kp + (t * 16 + lr) * 32 + lg * 8);
    qf[t] = *(const bf16x8*)(qp + (t * 16 + lr) * 32 + lg * 8);
  }

  const u32x4 zv = {0u, 0u, 0u, 0u};
#pragma unroll
  for (int c0 = 0; c0 < 4; ++c0) {
    const int c = c0 * 64 + lane;
    const int key = c >> 2, d0 = (c & 3) << 3;
    union { u32x4 v; unsigned short ss[8]; } tmp;
    tmp.v = (key < NWIN) ? *(const u32x4*)(vp + key * 32 + d0) : zv;
#pragma unroll
    for (int jj = 0; jj < 8; ++jj) vt[(d0 + jj) * 66 + key] = tmp.ss[jj];
  }

  const f32x4 fz = {0.f, 0.f, 0.f, 0.f};
  f32x4 s4[4][4];
#pragma unroll
  for (int mi = 0; mi < 4; ++mi)
#pragma unroll
    for (int ni = 0; ni < 4; ++ni) s4[mi][ni] = fz;
  __builtin_amdgcn_s_setprio(1);
#pragma unroll
  for (int mi = 0; mi < 4; ++mi)
#pragma unroll
    for (int ni = 0; ni < 4; ++ni)
      s4[mi][ni] = __builtin_amdgcn_mfma_f32_16x16x32_bf16(kf[mi], qf[ni], s4[mi][ni], 0, 0, 0);
  __builtin_amdgcn_s_setprio(0);

  union VU { unsigned int u[4]; bf16x8 v; };
  VU vfr[2][2];
#pragma unroll
  for (int nj = 0; nj < 2; ++nj)
#pragma unroll
    for (int ks = 0; ks < 2; ++ks) {
      const int base = ((16 * nj + lr) * 66 + 32 * ks + 8 * lg) >> 1;
#pragma unroll
      for (int u = 0; u < 4; ++u) vfr[nj][ks].u[u] = ((const unsigned int*)vt)[base + u];
    }

  __syncthreads();  // msk staged; drains vfr ds_reads (P may now reuse V region)

  const float scale = 0.1767766952966369f;
  const float* bp = biasP + ((size_t)h << 12);

  f32x4 o[4][2];
#pragma unroll
  for (int qi = 0; qi < 4; ++qi)
#pragma unroll
    for (int nj = 0; nj < 2; ++nj) o[qi][nj] = fz;

#pragma unroll
  for (int ni = 0; ni < 4; ++ni) {
    float v[16];
    float mx = -3e38f;
    const float* brow = &msk[(16 * ni + lr) * 66];
    const float* birow = bp + (16 * ni + lr) * 64;
#pragma unroll
    for (int mi = 0; mi < 4; ++mi) {
      const f32x4 bi4 = *(const f32x4*)(birow + 16 * mi + 4 * lg);
#pragma unroll
      for (int r = 0; r < 4; ++r) {
        v[mi * 4 + r] = fmaf(s4[mi][ni][r], scale, brow[16 * mi + 4 * lg + r]) + bi4[r];
        mx = fmaxf(mx, v[mi * 4 + r]);
      }
    }
    mx = fmaxf(mx, __shfl_xor(mx, 16));
    mx = fmaxf(mx, __shfl_xor(mx, 32));
    float sum = 0.f;
#pragma unroll
    for (int t = 0; t < 16; ++t) {
      v[t] = __expf(v[t] - mx);
      sum += v[t];
    }
    sum += __shfl_xor(sum, 16);
    sum += __shfl_xor(sum, 32);
    const float inv = __builtin_amdgcn_rcpf(sum);

    const int ip = 16 * (ni & 1) + lr;
#pragma unroll
    for (int mi = 0; mi < 4; ++mi) {
      const unsigned int lo = (unsigned int)f32_to_bf16(v[mi * 4 + 0] * inv) |
                              ((unsigned int)f32_to_bf16(v[mi * 4 + 1] * inv) << 16);
      const unsigned int hi = (unsigned int)f32_to_bf16(v[mi * 4 + 2] * inv) |
                              ((unsigned int)f32_to_bf16(v[mi * 4 + 3] * inv) << 16);
      const int byteoff = 32 * mi + 8 * lg;
      const int sw = byteoff ^ ((ip & 7) << 4);
      uint2 w2; w2.x = lo; w2.y = hi;
      *(uint2*)((char*)pl + ip * 128 + sw) = w2;
    }

    if (ni & 1) {
      asm volatile("s_waitcnt lgkmcnt(0)" ::: "memory");
      __builtin_amdgcn_sched_barrier(0);
      const int half = ni >> 1;
      __builtin_amdgcn_s_setprio(1);
#pragma unroll
      for (int q2 = 0; q2 < 2; ++q2) {
        const int qi = half * 2 + q2;
        const int ipr = 16 * q2 + lr;
#pragma unroll
        for (int ks = 0; ks < 2; ++ks) {
          const int bo = 64 * ks + 16 * lg;
          const int swr = bo ^ ((ipr & 7) << 4);
          const bf16x8 pa = *(const bf16x8*)((const char*)pl + ipr * 128 + swr);
#pragma unroll
          for (int nj = 0; nj < 2; ++nj)
            o[qi][nj] = __builtin_amdgcn_mfma_f32_16x16x32_bf16(pa, vfr[nj][ks].v, o[qi][nj], 0, 0, 0);
        }
      }
      __builtin_amdgcn_s_setprio(0);
    }
  }

  const size_t orow = (size_t)b * NWIN;
#pragma unroll
  for (int qi = 0; qi < 4; ++qi)
#pragma unroll
    for (int r = 0; r < 4; ++r) {
      const int i = 16 * qi + 4 * lg + r;
      if (i < NWIN) {
#pragma unroll
        for (int nj = 0; nj < 2; ++nj)
          aout[(orow + i) * C_DIM + h * HD + 16 * nj + lr] = f32_to_bf16(o[qi][nj][r]);
      }
    }
}

// ---------------------------------------------------------------- launch
static const size_t SZ_QKV = (size_t)M_ROWS * QKV_N * 2;   // 308 MB (blocked layout)
static const size_t SZ_XB  = (size_t)M_ROWS * C_DIM * 2;
static const size_t SZ_WQ  = (size_t)QKV_N * C_DIM * 2;
static const size_t SZ_WP  = (size_t)C_DIM * C_DIM * 2;
static const size_t OFF_QKV = 0;
static const size_t OFF_XB  = OFF_QKV + SZ_QKV;   // x_bf16, later attn_out
static const size_t OFF_WQ  = OFF_XB + SZ_XB;
static const size_t OFF_WP  = OFF_WQ + SZ_WQ;
static const size_t OFF_MSK = OFF_WP + SZ_WP;                    // 64*4096 f32 = 1 MB
static const size_t OFF_BIA = OFF_MSK + (size_t)64 * 4096 * 4;   // 16*4096 f32 = 256 KB

extern "C" void kernel_launch(void* const* d_in, const int* in_sizes, int n_in,
                              void* d_out, int out_size, void* d_ws, size_t ws_size,
                              hipStream_t stream) {
  const float* x      = (const float*)d_in[0];
  const float* mask   = (const float*)d_in[1];
  const float* qkv_w  = (const float*)d_in[2];
  const float* qkv_b  = (const float*)d_in[3];
  const float* proj_w = (const float*)d_in[4];
  const float* proj_b = (const float*)d_in[5];
  const float* rel    = (const float*)d_in[6];
  float* out = (float*)d_out;

  char* ws = (char*)d_ws;
  unsigned short* qkvb = (unsigned short*)(ws + OFF_QKV);
  unsigned short* xb   = (unsigned short*)(ws + OFF_XB);
  unsigned short* wqT  = (unsigned short*)(ws + OFF_WQ);
  unsigned short* wpT  = (unsigned short*)(ws + OFF_WP);
  float*          mskP = (float*)(ws + OFF_MSK);
  float*          biasP= (float*)(ws + OFF_BIA);

  k_cvt<<<2048, 256, 0, stream>>>(x, xb, M_ROWS * C_DIM / 4);
  k_transpose_cvt<<<dim3(QKV_N / 32, C_DIM / 32), 256, 0, stream>>>(qkv_w, wqT, C_DIM, QKV_N);
  k_transpose_cvt<<<dim3(C_DIM / 32, C_DIM / 32), 256, 0, stream>>>(proj_w, wpT, C_DIM, C_DIM);
  k_mskp<<<(64 * 4096) / 256, 256, 0, stream>>>(mask, mskP);
  k_biasp<<<(16 * 4096) / 256, 256, 0, stream>>>(rel, biasP);

  // qkv = x @ qkv_w + qkv_b  (bf16, blocked layout), grid 6*392 = 2352 (%8==0)
  k_gemm_qkv<<<(QKV_N / 256) * (M_ROWS / 256), 512, 0, stream>>>(
      xb, wqT, qkv_b, qkvb, M_ROWS, QKV_N, C_DIM);

  // attention -> attn_out (reuses xb region), 4096 blocks of 512 thr
  k_attn<<<2048 * 2, 512, 0, stream>>>(qkvb, mskP, biasP, xb);

  // out = attn_out @ proj_w + proj_b  (f32 out), grid 2*392 = 784 (%8==0)
  k_gemm_proj<<<(C_DIM / 256) * (M_ROWS / 256), 512, 0, stream>>>(
      xb, wpT, proj_b, out, M_ROWS, C_DIM, C_DIM);
}

// Round 17
// 492.539 us; speedup vs baseline: 1.0320x; 1.0320x over previous
//
#include <hip/hip_runtime.h>
#include <hip/hip_bf16.h>
#include <stdint.h>

// Problem constants (match setup_inputs)
#define M_ROWS 100352   // 2048 * 49
#define C_DIM  512
#define QKV_N  1536
#define NH     16
#define HD     32
#define NWIN   49       // window tokens (7*7)
#define NMASK  64

typedef __attribute__((ext_vector_type(4))) float        f32x4;
typedef __attribute__((ext_vector_type(8))) short        bf16x8;
typedef __attribute__((ext_vector_type(4))) unsigned int u32x4;

static __device__ __forceinline__ unsigned short f32_to_bf16(float f) {
  union { float f; unsigned int u; } v; v.f = f;
  unsigned int u = v.u;
  return (unsigned short)((u + 0x7FFFu + ((u >> 16) & 1u)) >> 16);  // RNE
}

// global -> LDS direct DMA, 16B per lane. dest = wave-uniform base + lane*16.
static __device__ __forceinline__ void gload_lds16(const void* g, void* l) {
  __builtin_amdgcn_global_load_lds(
      (const __attribute__((address_space(1))) unsigned int*)g,
      (__attribute__((address_space(3))) unsigned int*)l, 16, 0, 0);
}

// ---------------------------------------------------------------- k_cvt
__global__ void k_cvt(const float* __restrict__ in, unsigned short* __restrict__ out, int n4) {
  int i = blockIdx.x * blockDim.x + threadIdx.x;
  int stride = gridDim.x * blockDim.x;
  for (; i < n4; i += stride) {
    float4 v = ((const float4*)in)[i];
    ushort4 o = make_ushort4(f32_to_bf16(v.x), f32_to_bf16(v.y),
                             f32_to_bf16(v.z), f32_to_bf16(v.w));
    ((ushort4*)out)[i] = o;
  }
}

// ------------------------------------------- transpose + convert weights
// in: K x N f32 (row-major), out: N x K bf16 (row-major) == B^T
__global__ void k_transpose_cvt(const float* __restrict__ in, unsigned short* __restrict__ out,
                                int K, int N) {
  __shared__ float t[32][33];
  const int n0 = blockIdx.x * 32, k0 = blockIdx.y * 32;
  const int tx = threadIdx.x & 31, ty = threadIdx.x >> 5;  // 32 x 8
#pragma unroll
  for (int rr = 0; rr < 32; rr += 8)
    t[ty + rr][tx] = in[(size_t)(k0 + ty + rr) * N + n0 + tx];
  __syncthreads();
#pragma unroll
  for (int rr = 0; rr < 32; rr += 8)
    out[(size_t)(n0 + ty + rr) * K + k0 + tx] = f32_to_bf16(t[tx][ty + rr]);
}

// ----------------------------------------- fused bias+mask table (padded)
__global__ __launch_bounds__(256) void k_bm(const float* __restrict__ mask,
                                            const float* __restrict__ rel,
                                            float* __restrict__ bmt) {
  const int idx = blockIdx.x * 256 + threadIdx.x;   // w<<16 | h<<12 | i<<6 | j
  const int j = idx & 63, i = (idx >> 6) & 63, h = (idx >> 12) & 15, w = idx >> 16;
  float v = -1e30f;
  if (i < NWIN && j < NWIN) {
    const int rpi = ((j / 7) - (i / 7) + 6) * 13;
    v = mask[w * (NWIN * NWIN) + i * NWIN + j] + rel[rpi * NH + h];
  }
  bmt[idx] = v;
}

#define WAITB(N)                                              \
  do {                                                        \
    asm volatile("s_waitcnt vmcnt(" #N ")" ::: "memory");     \
    __builtin_amdgcn_sched_barrier(0);                        \
    __builtin_amdgcn_s_barrier();                             \
    __builtin_amdgcn_sched_barrier(0);                        \
  } while (0)

// ------------------------------------------------------------------ GEMM
// EXACT r5/r12 4-phase 256x256 K-loop (schedule-fragile; never touched).
// OUT_MODE: 0 = f32 row-major, 1 = bf16 row-major,
//           2 = bf16 qkv-blocked [b][h][{q,k,v}][49][32] (attn-friendly).
template <int OUT_MODE>
static __device__ __forceinline__ void gemm256_body(const unsigned short* __restrict__ A,
                                                    const unsigned short* __restrict__ BT,
                                                    const float* __restrict__ bias,
                                                    void* __restrict__ Cout,
                                                    int M, int N, int K,
                                                    unsigned short* lds0) {
  unsigned short (*lds)[2][16384] = (unsigned short (*)[2][16384])lds0;
  const int tid = threadIdx.x;
  const int lane = tid & 63, wave = tid >> 6;
  const int wr = wave >> 2, wc = wave & 3;      // 2 x 4 wave grid
  const int lr = lane & 15, lg = lane >> 4;

  // bijective XCD swizzle (gridDim.x % 8 == 0 for all call sites)
  const int nwg = gridDim.x, q8 = nwg >> 3;
  const int wg = (blockIdx.x & 7) * q8 + (blockIdx.x >> 3);
  const int gx = N >> 8;
  const int bx = wg % gx, by = wg / gx;
  const int m0 = by << 8, n0 = bx << 8;

  const int srow = lane & 15;
  const int scol = (lane >> 4) * 8;
  const int sRG = wave >> 1;
  const int scg = wave & 1;

  const f32x4 fz = {0.f, 0.f, 0.f, 0.f};
  f32x4 acc[8][4];
#pragma unroll
  for (int i = 0; i < 8; ++i)
#pragma unroll
    for (int j = 0; j < 4; ++j) acc[i][j] = fz;

  const int NT = K >> 6;

  auto stageU = [&](const unsigned short* G, int gbase, int op, int t, int u) {
    const int RG = 4 * u + sRG;  // row-group 0..15
    gload_lds16(G + (size_t)(gbase + RG * 16 + srow) * K + (t << 6) + scg * 32 + scol,
                &lds[t & 1][op][(RG >> 3) * 8192 + (((RG & 7) << 1) + scg) * 512]);
  };

  const int roff = lg * 128 + lr * 8;

  bf16x8 af[4][2];
  bf16x8 bf[2][2];
  bf16x8 bg[2][2];

#define LDA(h, mh)                                                              \
  do {                                                                          \
    const unsigned short* la = &lds[(h) & 1][0][wr * 8192];                     \
    _Pragma("unroll") for (int m = 0; m < 4; ++m)                               \
    _Pragma("unroll") for (int ks = 0; ks < 2; ++ks)                            \
        af[m][ks] = *(const bf16x8*)(la + ((((mh)*4 + m) * 2 + ks) * 512) + roff); \
  } while (0)

#define LDB(h, nh, DST)                                                         \
  do {                                                                          \
    const unsigned short* lb = &lds[(h) & 1][1][(wc >> 1) * 8192];              \
    _Pragma("unroll") for (int n = 0; n < 2; ++n)                               \
    _Pragma("unroll") for (int ks = 0; ks < 2; ++ks)                            \
        DST[n][ks] = *(const bf16x8*)(lb + ((((wc & 1) * 4 + (nh)*2 + n) * 2 + ks) * 512) + roff); \
  } while (0)

#define MFMA16(mh, nh, B)                                                       \
  do {                                                                          \
    __builtin_amdgcn_s_setprio(1);                                              \
    _Pragma("unroll") for (int m = 0; m < 4; ++m)                               \
    _Pragma("unroll") for (int n = 0; n < 2; ++n)                               \
    _Pragma("unroll") for (int ks = 0; ks < 2; ++ks)                            \
        acc[(mh)*4 + m][(nh)*2 + n] = __builtin_amdgcn_mfma_f32_16x16x32_bf16(  \
            af[m][ks], B[n][ks], acc[(mh)*4 + m][(nh)*2 + n], 0, 0, 0);         \
    __builtin_amdgcn_s_setprio(0);                                              \
  } while (0)

  // prologue: tile 0, unit order B0 B1 B2 B3 A0 A2 A1 A3 (8 loads/lane)
  stageU(BT, n0, 1, 0, 0); stageU(BT, n0, 1, 0, 1);
  stageU(BT, n0, 1, 0, 2); stageU(BT, n0, 1, 0, 3);
  stageU(A,  m0, 0, 0, 0); stageU(A,  m0, 0, 0, 2);
  stageU(A,  m0, 0, 0, 1); stageU(A,  m0, 0, 0, 3);

  for (int h = 0; h < NT - 1; ++h) {
    const int t1 = h + 1;
    WAITB(2);
    stageU(BT, n0, 1, t1, 0); stageU(BT, n0, 1, t1, 1);
    LDA(h, 0);
    LDB(h, 0, bf);
    MFMA16(0, 0, bf);
    stageU(BT, n0, 1, t1, 2); stageU(BT, n0, 1, t1, 3);
    LDB(h, 1, bg);
    MFMA16(0, 1, bg);
    WAITB(4);
    stageU(A, m0, 0, t1, 0); stageU(A, m0, 0, t1, 2);
    LDA(h, 1);
    MFMA16(1, 1, bg);
    stageU(A, m0, 0, t1, 1); stageU(A, m0, 0, t1, 3);
    LDB(h, 0, bf);
    MFMA16(1, 0, bf);
  }
  {  // last tile, peeled
    const int h = NT - 1;
    WAITB(2);
    LDA(h, 0);
    LDB(h, 0, bf);
    MFMA16(0, 0, bf);
    LDB(h, 1, bg);
    MFMA16(0, 1, bg);
    WAITB(0);
    LDA(h, 1);
    MFMA16(1, 1, bg);
    LDB(h, 0, bf);
    MFMA16(1, 0, bf);
  }
#undef LDA
#undef LDB
#undef MFMA16

  float bv[4];
#pragma unroll
  for (int nj = 0; nj < 4; ++nj) bv[nj] = bias[n0 + wc * 64 + nj * 16 + lr];
#pragma unroll
  for (int mi = 0; mi < 8; ++mi)
#pragma unroll
    for (int nj = 0; nj < 4; ++nj)
#pragma unroll
      for (int r = 0; r < 4; ++r) {
        const int row = m0 + wr * 128 + mi * 16 + 4 * lg + r;
        const int col = n0 + wc * 64 + nj * 16 + lr;
        const float v = acc[mi][nj][r] + bv[nj];
        if (OUT_MODE == 2) {
          // qkv-blocked: row -> (b = row/49, i = row%49); col -> (which, h, d)
          const unsigned int b = (unsigned int)row / 49u;
          const unsigned int i = (unsigned int)row - b * 49u;
          const int which = col >> 9, hh = (col >> 5) & 15, d = col & 31;
          ((unsigned short*)Cout)[(((size_t)b * NH + hh) * 147 + which * 49 + i) * 32 + d] =
              f32_to_bf16(v);
        } else if (OUT_MODE == 1) {
          ((unsigned short*)Cout)[(size_t)row * N + col] = f32_to_bf16(v);
        } else {
          ((float*)Cout)[(size_t)row * N + col] = v;
        }
      }
}

__global__ __launch_bounds__(512, 2) void k_gemm_qkv(const unsigned short* __restrict__ A,
                                                     const unsigned short* __restrict__ BT,
                                                     const float* __restrict__ bias,
                                                     void* __restrict__ Cout,
                                                     int M, int N, int K) {
  __shared__ __align__(16) unsigned short lds[2][2][16384];  // 128 KB
  gemm256_body<2>(A, BT, bias, Cout, M, N, K, &lds[0][0][0]);
}

__global__ __launch_bounds__(512, 2) void k_gemm_proj(const unsigned short* __restrict__ A,
                                                      const unsigned short* __restrict__ BT,
                                                      const float* __restrict__ bias,
                                                      void* __restrict__ Cout,
                                                      int M, int N, int K) {
  __shared__ __align__(16) unsigned short lds[2][2][16384];  // 128 KB
  gemm256_body<0>(A, BT, bias, Cout, M, N, K, &lds[0][0][0]);
}

// ------------------------------------------------------------- attention
// r14-proven best (attn ~117 us): block = (w, h, tg), 4 waves handle
// b = w + 64*(4*tg + wave) sharing one LDS-staged (w,h) bias+mask table;
// XCD swizzle clusters w so per-XCD table set (2 MB) is L2-resident.
// qkv in blocked layout [b][h][{q,k,v}][49][32] (r13).
__global__ __launch_bounds__(256) void k_attn(const unsigned short* __restrict__ qkv,
                                              const float* __restrict__ bmt,
                                              unsigned short* __restrict__ aout) {
  const int wave = threadIdx.x >> 6, lane = threadIdx.x & 63;
  const int lr = lane & 15, lg = lane >> 4;

  // bijective XCD swizzle over 8192 blocks (q8 = 1024): XCD x gets
  // s in [1024x, 1024x+1024) -> w in [8x, 8x+8).
  const int s = (blockIdx.x & 7) * 1024 + (blockIdx.x >> 3);
  const int w = s >> 7, h = (s >> 3) & 15, tg = s & 7;
  const int b = w + 64 * (tg * 4 + wave);

  __shared__ float bml[64 * 66];                        // 16.9 KB shared table
  __shared__ __align__(16) unsigned short Pl[4][2048];  // per-wave P
  __shared__ __align__(16) unsigned short Vt[4][2112];  // per-wave V^T
  unsigned short* pl = Pl[wave];
  unsigned short* vt = Vt[wave];

  // ---- stage bmt(w,h) -> LDS (coalesced 16 KB read; issued first) ----
  const float* tbl = bmt + ((size_t)(w * NH + h) << 12);
#pragma unroll
  for (int it = 0; it < 4; ++it) {
    const int c = threadIdx.x + 256 * it;   // 16B chunk 0..1023
    const int row = c >> 4, col4 = c & 15;
    const f32x4 t4 = *(const f32x4*)(tbl + row * 64 + col4 * 4);
    float* dst = &bml[row * 66 + col4 * 4];
    dst[0] = t4[0]; dst[1] = t4[1]; dst[2] = t4[2]; dst[3] = t4[3];
  }

  const unsigned short* qp = qkv + ((size_t)(b * NH + h) * 147) * 32;
  const unsigned short* kp = qp + 49 * 32;
  const unsigned short* vp = qp + 2 * 49 * 32;

  bf16x8 kf[4], qf[4];
#pragma unroll
  for (int t = 0; t < 4; ++t) {
    kf[t] = *(const bf16x8*)(kp + (t * 16 + lr) * 32 + lg * 8);
    qf[t] = *(const bf16x8*)(qp + (t * 16 + lr) * 32 + lg * 8);
  }

  const u32x4 zv = {0u, 0u, 0u, 0u};
#pragma unroll
  for (int c0 = 0; c0 < 4; ++c0) {
    const int c = c0 * 64 + lane;
    const int key = c >> 2, d0 = (c & 3) << 3;
    union { u32x4 v; unsigned short ss[8]; } tmp;
    tmp.v = (key < NWIN) ? *(const u32x4*)(vp + key * 32 + d0) : zv;
#pragma unroll
    for (int jj = 0; jj < 8; ++jj) vt[(d0 + jj) * 66 + key] = tmp.ss[jj];
  }

  const f32x4 fz = {0.f, 0.f, 0.f, 0.f};
  f32x4 s4[4][4];
#pragma unroll
  for (int mi = 0; mi < 4; ++mi)
#pragma unroll
    for (int ni = 0; ni < 4; ++ni) s4[mi][ni] = fz;
#pragma unroll
  for (int mi = 0; mi < 4; ++mi)
#pragma unroll
    for (int ni = 0; ni < 4; ++ni)
      s4[mi][ni] = __builtin_amdgcn_mfma_f32_16x16x32_bf16(kf[mi], qf[ni], s4[mi][ni], 0, 0, 0);

  union VU { unsigned int u[4]; bf16x8 v; };
  VU vfr[2][2];
#pragma unroll
  for (int nj = 0; nj < 2; ++nj)
#pragma unroll
    for (int ks = 0; ks < 2; ++ks) {
      const int base = ((16 * nj + lr) * 66 + 32 * ks + 8 * lg) >> 1;
#pragma unroll
      for (int u = 0; u < 4; ++u) vfr[nj][ks].u[u] = ((const unsigned int*)vt)[base + u];
    }

  __syncthreads();  // bml staged (QK^T hid the latency)

  const float scale = 0.1767766952966369f;

  f32x4 o[4][2];
#pragma unroll
  for (int qi = 0; qi < 4; ++qi)
#pragma unroll
    for (int nj = 0; nj < 2; ++nj) o[qi][nj] = fz;

#pragma unroll
  for (int ni = 0; ni < 4; ++ni) {
    float v[16];
    float mx = -3e38f;
    const float* brow = &bml[(16 * ni + lr) * 66];
#pragma unroll
    for (int mi = 0; mi < 4; ++mi) {
#pragma unroll
      for (int r = 0; r < 4; ++r) {
        v[mi * 4 + r] = fmaf(s4[mi][ni][r], scale, brow[16 * mi + 4 * lg + r]);
        mx = fmaxf(mx, v[mi * 4 + r]);
      }
    }
    mx = fmaxf(mx, __shfl_xor(mx, 16));
    mx = fmaxf(mx, __shfl_xor(mx, 32));
    float sum = 0.f;
#pragma unroll
    for (int t = 0; t < 16; ++t) {
      v[t] = __expf(v[t] - mx);
      sum += v[t];
    }
    sum += __shfl_xor(sum, 16);
    sum += __shfl_xor(sum, 32);
    const float inv = __builtin_amdgcn_rcpf(sum);

    const int ip = 16 * (ni & 1) + lr;
#pragma unroll
    for (int mi = 0; mi < 4; ++mi) {
      const unsigned int lo = (unsigned int)f32_to_bf16(v[mi * 4 + 0] * inv) |
                              ((unsigned int)f32_to_bf16(v[mi * 4 + 1] * inv) << 16);
      const unsigned int hi = (unsigned int)f32_to_bf16(v[mi * 4 + 2] * inv) |
                              ((unsigned int)f32_to_bf16(v[mi * 4 + 3] * inv) << 16);
      const int byteoff = 32 * mi + 8 * lg;
      const int sw = byteoff ^ ((ip & 7) << 4);
      uint2 w2; w2.x = lo; w2.y = hi;
      *(uint2*)((char*)pl + ip * 128 + sw) = w2;
    }

    if (ni & 1) {
      asm volatile("s_waitcnt lgkmcnt(0)" ::: "memory");
      __builtin_amdgcn_sched_barrier(0);
      const int half = ni >> 1;
#pragma unroll
      for (int q2 = 0; q2 < 2; ++q2) {
        const int qi = half * 2 + q2;
        const int ipr = 16 * q2 + lr;
#pragma unroll
        for (int ks = 0; ks < 2; ++ks) {
          const int bo = 64 * ks + 16 * lg;
          const int swr = bo ^ ((ipr & 7) << 4);
          const bf16x8 pa = *(const bf16x8*)((const char*)pl + ipr * 128 + swr);
#pragma unroll
          for (int nj = 0; nj < 2; ++nj)
            o[qi][nj] = __builtin_amdgcn_mfma_f32_16x16x32_bf16(pa, vfr[nj][ks].v, o[qi][nj], 0, 0, 0);
        }
      }
    }
  }

  const size_t orow = (size_t)b * NWIN;
#pragma unroll
  for (int qi = 0; qi < 4; ++qi)
#pragma unroll
    for (int r = 0; r < 4; ++r) {
      const int i = 16 * qi + 4 * lg + r;
      if (i < NWIN) {
#pragma unroll
        for (int nj = 0; nj < 2; ++nj)
          aout[(orow + i) * C_DIM + h * HD + 16 * nj + lr] = f32_to_bf16(o[qi][nj][r]);
      }
    }
}

// ---------------------------------------------------------------- launch
static const size_t SZ_QKV = (size_t)M_ROWS * QKV_N * 2;   // 308 MB (blocked layout)
static const size_t SZ_XB  = (size_t)M_ROWS * C_DIM * 2;
static const size_t SZ_WQ  = (size_t)QKV_N * C_DIM * 2;
static const size_t OFF_QKV = 0;
static const size_t OFF_XB  = OFF_QKV + SZ_QKV;   // x_bf16, later attn_out
static const size_t OFF_WQ  = OFF_XB + SZ_XB;
static const size_t OFF_WP  = OFF_WQ + SZ_WQ;

extern "C" void kernel_launch(void* const* d_in, const int* in_sizes, int n_in,
                              void* d_out, int out_size, void* d_ws, size_t ws_size,
                              hipStream_t stream) {
  const float* x      = (const float*)d_in[0];
  const float* mask   = (const float*)d_in[1];
  const float* qkv_w  = (const float*)d_in[2];
  const float* qkv_b  = (const float*)d_in[3];
  const float* proj_w = (const float*)d_in[4];
  const float* proj_b = (const float*)d_in[5];
  const float* rel    = (const float*)d_in[6];
  float* out = (float*)d_out;

  char* ws = (char*)d_ws;
  unsigned short* qkvb = (unsigned short*)(ws + OFF_QKV);
  unsigned short* xb   = (unsigned short*)(ws + OFF_XB);
  unsigned short* wqT  = (unsigned short*)(ws + OFF_WQ);
  unsigned short* wpT  = (unsigned short*)(ws + OFF_WP);
  // bmt (16.78 MB) in d_out scratch: fully consumed by k_attn before final GEMM.
  float* bmt = (float*)d_out;

  k_cvt<<<2048, 256, 0, stream>>>(x, xb, M_ROWS * C_DIM / 4);
  k_transpose_cvt<<<dim3(QKV_N / 32, C_DIM / 32), 256, 0, stream>>>(qkv_w, wqT, C_DIM, QKV_N);
  k_transpose_cvt<<<dim3(C_DIM / 32, C_DIM / 32), 256, 0, stream>>>(proj_w, wpT, C_DIM, C_DIM);
  k_bm<<<(NMASK * NH * 64 * 64) / 256, 256, 0, stream>>>(mask, rel, bmt);

  // qkv = x @ qkv_w + qkv_b  (bf16, blocked layout), grid 6*392 = 2352 (%8==0)
  k_gemm_qkv<<<(QKV_N / 256) * (M_ROWS / 256), 512, 0, stream>>>(
      xb, wqT, qkv_b, qkvb, M_ROWS, QKV_N, C_DIM);

  // attention -> attn_out (reuses xb region), 8192 blocks (%8==0)
  k_attn<<<NMASK * NH * 8, 256, 0, stream>>>(qkvb, bmt, xb);

  // out = attn_out @ proj_w + proj_b  (f32 out), grid 2*392 = 784 (%8==0)
  k_gemm_proj<<<(C_DIM / 256) * (M_ROWS / 256), 512, 0, stream>>>(
      xb, wpT, proj_b, out, M_ROWS, C_DIM, C_DIM);
}